// Round 1
// baseline (760.662 us; speedup 1.0000x reference)
//
#include <hip/hip_runtime.h>

#define N_NODES 100000
#define N_EDGES 1600000
#define NB      50
#define GSIZE   2000
#define FEAT    128
#define NC      10
#define SCAN_BLOCKS 98   // ceil(100000/1024)

// ---------------- degree count ----------------
__global__ void k_count(const int* __restrict__ dst, int* __restrict__ deg) {
    int e = blockIdx.x * blockDim.x + threadIdx.x;
    atomicAdd(&deg[dst[e]], 1);
}

// ---------------- scan (3-phase) ----------------
__global__ void k_scan1(const int* __restrict__ deg, int* __restrict__ bsum) {
    __shared__ int red[256];
    int base = blockIdx.x * 1024;
    int tid = threadIdx.x;
    int s = 0;
    for (int q = 0; q < 4; ++q) {
        int idx = base + tid * 4 + q;
        if (idx < N_NODES) s += deg[idx];
    }
    red[tid] = s; __syncthreads();
    for (int off = 128; off > 0; off >>= 1) {
        if (tid < off) red[tid] += red[tid + off];
        __syncthreads();
    }
    if (tid == 0) bsum[blockIdx.x] = red[0];
}

__global__ void k_scan2(int* __restrict__ bsum, int nb, int* __restrict__ rowstart) {
    if (threadIdx.x == 0) {
        int run = 0;
        for (int i = 0; i < nb; ++i) { int t = bsum[i]; bsum[i] = run; run += t; }
        rowstart[N_NODES] = run;   // == E
    }
}

__global__ void k_scan3(const int* __restrict__ deg, const int* __restrict__ bsum,
                        int* __restrict__ rowstart, int* __restrict__ cursor,
                        float* __restrict__ dinv) {
    __shared__ int tsum[256];
    int tid = threadIdx.x;
    int base = blockIdx.x * 1024;
    int v[4]; int tot = 0;
    for (int q = 0; q < 4; ++q) {
        int idx = base + tid * 4 + q;
        v[q] = (idx < N_NODES) ? deg[idx] : 0;
        tot += v[q];
    }
    tsum[tid] = tot; __syncthreads();
    for (int off = 1; off < 256; off <<= 1) {
        int t = (tid >= off) ? tsum[tid - off] : 0;
        __syncthreads();
        tsum[tid] += t;
        __syncthreads();
    }
    int run = bsum[blockIdx.x] + tsum[tid] - tot;  // exclusive prefix for this thread
    for (int q = 0; q < 4; ++q) {
        int idx = base + tid * 4 + q;
        if (idx < N_NODES) {
            rowstart[idx] = run;
            cursor[idx]   = run;
            dinv[idx]     = rsqrtf(fmaxf((float)v[q], 1.0f));
            run += v[q];
        }
    }
}

__global__ void k_fill(const int* __restrict__ src, const int* __restrict__ dst,
                       int* __restrict__ cursor, int* __restrict__ csrc) {
    int e = blockIdx.x * blockDim.x + threadIdx.x;
    int p = atomicAdd(&cursor[dst[e]], 1);
    csrc[p] = src[e];
}

// ---------------- gather SpMM: T1[n] = -dinv[n] * sum_{e: dst=n} X[src]*dinv[src] ----
__global__ __launch_bounds__(256) void k_gather(
    const float* __restrict__ X, const float* __restrict__ dinv,
    const int* __restrict__ rowstart, const int* __restrict__ csrc,
    float* __restrict__ T1) {
    int tid = threadIdx.x;
    int c = tid & 31;          // float4 column 0..31
    int i = tid >> 5;          // node 0..7 within block
    int n = blockIdx.x * 8 + i;
    int rs = rowstart[n], re = rowstart[n + 1];
    const float4* X4 = (const float4*)X;
    float4 acc = make_float4(0.f, 0.f, 0.f, 0.f);
    for (int e = rs; e < re; ++e) {
        int s = csrc[e];
        float dv = dinv[s];
        float4 v = X4[s * 32 + c];
        acc.x += v.x * dv; acc.y += v.y * dv;
        acc.z += v.z * dv; acc.w += v.w * dv;
    }
    float dn = -dinv[n];
    float4 o; o.x = acc.x * dn; o.y = acc.y * dn; o.z = acc.z * dn; o.w = acc.w * dn;
    ((float4*)T1)[n * 32 + c] = o;
}

// ---------------- fused Cheb GEMM: OUT = relu([X, T1] @ W + b), W is (256,128) ------
#define GM 32
__global__ __launch_bounds__(256) void k_gemm(
    const float* __restrict__ X, const float* __restrict__ T1,
    const float* __restrict__ W, const float* __restrict__ bias,
    float* __restrict__ OUT) {
    __shared__ float As[16][GM];     // [kk][n]
    __shared__ float Bs[16][128];    // [kk][j]
    int tid = threadIdx.x;
    int n0 = blockIdx.x * GM;
    int tj = tid & 31;   // cols 4*tj .. 4*tj+3
    int tn = tid >> 5;   // nodes 4*tn .. 4*tn+3 (0..7)
    float acc[4][4] = {{0.f}};

    for (int kb = 0; kb < 256; kb += 16) {
        const float* src = (kb < 128) ? (X + kb) : (T1 + (kb - 128));
        // A tile: 32 nodes x 16 k, stored transposed As[kk][n]
        {
            int i = tid;
            #pragma unroll
            for (int r = 0; r < 2; ++r, i += 256) {
                int n = i >> 4, kk = i & 15;
                As[kk][n] = src[(n0 + n) * FEAT + kk];
            }
        }
        // B tile: 16 x 128
        {
            int j4 = tid & 31, kk = tid >> 5;   // kk 0..7
            *((float4*)&Bs[kk][j4 * 4])     = *((const float4*)(W + (kb + kk) * FEAT + j4 * 4));
            *((float4*)&Bs[kk + 8][j4 * 4]) = *((const float4*)(W + (kb + kk + 8) * FEAT + j4 * 4));
        }
        __syncthreads();
        #pragma unroll
        for (int r = 0; r < 16; ++r) {
            float4 a  = *((const float4*)&As[r][tn * 4]);
            float4 bv = *((const float4*)&Bs[r][tj * 4]);
            acc[0][0] += a.x * bv.x; acc[0][1] += a.x * bv.y; acc[0][2] += a.x * bv.z; acc[0][3] += a.x * bv.w;
            acc[1][0] += a.y * bv.x; acc[1][1] += a.y * bv.y; acc[1][2] += a.y * bv.z; acc[1][3] += a.y * bv.w;
            acc[2][0] += a.z * bv.x; acc[2][1] += a.z * bv.y; acc[2][2] += a.z * bv.z; acc[2][3] += a.z * bv.w;
            acc[3][0] += a.w * bv.x; acc[3][1] += a.w * bv.y; acc[3][2] += a.w * bv.z; acc[3][3] += a.w * bv.w;
        }
        __syncthreads();
    }
    float4 bb = ((const float4*)bias)[tj];
    #pragma unroll
    for (int m = 0; m < 4; ++m) {
        int n = n0 + tn * 4 + m;
        float4 o;
        o.x = fmaxf(acc[m][0] + bb.x, 0.f);
        o.y = fmaxf(acc[m][1] + bb.y, 0.f);
        o.z = fmaxf(acc[m][2] + bb.z, 0.f);
        o.w = fmaxf(acc[m][3] + bb.w, 0.f);
        ((float4*)(OUT + n * FEAT))[tj] = o;
    }
}

// ---------------- segment max (graphs are contiguous 2000-node blocks) -------------
__global__ void k_segmax(const float* __restrict__ h, float* __restrict__ hg) {
    int g = blockIdx.x, ch = blockIdx.y;
    int j = threadIdx.x;
    int n0 = g * GSIZE + ch * 250;
    float m = 0.f;
    for (int i = 0; i < 250; ++i) m = fmaxf(m, h[(n0 + i) * FEAT + j]);
    atomicMax((int*)&hg[g * FEAT + j], __float_as_int(m));  // valid: all values >= 0
}

// ---------------- classifier ----------------
__global__ void k_classify(const float* __restrict__ hg, const float* __restrict__ Wc,
                           const float* __restrict__ bc, float* __restrict__ out) {
    int g = blockIdx.x, t = threadIdx.x;
    if (t < NC) {
        float acc = bc[t];
        for (int j = 0; j < FEAT; ++j) acc += hg[g * FEAT + j] * Wc[j * NC + t];
        out[g * NC + t] = acc;
    }
}

extern "C" void kernel_launch(void* const* d_in, const int* in_sizes, int n_in,
                              void* d_out, int out_size, void* d_ws, size_t ws_size,
                              hipStream_t stream) {
    const float* x   = (const float*)d_in[0];
    const float* W1  = (const float*)d_in[1];
    const float* b1  = (const float*)d_in[2];
    const float* W2  = (const float*)d_in[3];
    const float* b2  = (const float*)d_in[4];
    const float* Wc  = (const float*)d_in[5];
    const float* bc  = (const float*)d_in[6];
    const int*   src = (const int*)d_in[7];
    const int*   dst = (const int*)d_in[8];
    float* out = (float*)d_out;

    char* ws = (char*)d_ws;
    size_t off = 0;
    auto alloc = [&](size_t bytes) { char* p = ws + off; off += (bytes + 255) & ~(size_t)255; return p; };
    int*   deg      = (int*)  alloc(N_NODES * 4);
    float* dinv     = (float*)alloc(N_NODES * 4);
    int*   rowstart = (int*)  alloc((N_NODES + 1) * 4);
    int*   cursor   = (int*)  alloc(N_NODES * 4);
    int*   bsum     = (int*)  alloc(256 * 4);
    int*   csrc     = (int*)  alloc((size_t)N_EDGES * 4);
    float* t1       = (float*)alloc((size_t)N_NODES * FEAT * 4);
    float* h        = (float*)alloc((size_t)N_NODES * FEAT * 4);
    float* hg       = (float*)alloc(NB * FEAT * 4);

    hipMemsetAsync(deg, 0, N_NODES * 4, stream);
    k_count<<<N_EDGES / 256, 256, 0, stream>>>(dst, deg);
    k_scan1<<<SCAN_BLOCKS, 256, 0, stream>>>(deg, bsum);
    k_scan2<<<1, 64, 0, stream>>>(bsum, SCAN_BLOCKS, rowstart);
    k_scan3<<<SCAN_BLOCKS, 256, 0, stream>>>(deg, bsum, rowstart, cursor, dinv);
    k_fill<<<N_EDGES / 256, 256, 0, stream>>>(src, dst, cursor, csrc);

    // layer 1
    k_gather<<<N_NODES / 8, 256, 0, stream>>>(x, dinv, rowstart, csrc, t1);
    k_gemm<<<N_NODES / GM, 256, 0, stream>>>(x, t1, W1, b1, h);
    // layer 2 (h updated in place: each block reads only its own rows before writing)
    k_gather<<<N_NODES / 8, 256, 0, stream>>>(h, dinv, rowstart, csrc, t1);
    k_gemm<<<N_NODES / GM, 256, 0, stream>>>(h, t1, W2, b2, h);

    hipMemsetAsync(hg, 0, NB * FEAT * 4, stream);
    k_segmax<<<dim3(NB, 8), FEAT, 0, stream>>>(h, hg);
    k_classify<<<NB, 64, 0, stream>>>(hg, Wc, bc, out);
}

// Round 2
// 640.799 us; speedup vs baseline: 1.1871x; 1.1871x over previous
//
#include <hip/hip_runtime.h>

#define N_NODES 100000
#define N_EDGES 1600000
#define NB      50
#define GSIZE   2000
#define FEAT    128
#define NC      10
#define SCAN_BLOCKS 98   // ceil(100000/1024)

using short8 = __attribute__((ext_vector_type(8))) short;
using f32x4  = __attribute__((ext_vector_type(4))) float;

__device__ __forceinline__ unsigned bf16rnd(float f) {
    unsigned u = __float_as_uint(f);
    return (u + 0x7fffu + ((u >> 16) & 1u)) >> 16;   // RNE bf16 bits
}

// ---------------- degree count ----------------
__global__ void k_count(const int* __restrict__ dst, int* __restrict__ deg) {
    int e = blockIdx.x * blockDim.x + threadIdx.x;
    atomicAdd(&deg[dst[e]], 1);
}

// ---------------- scan (3-phase) ----------------
__global__ void k_scan1(const int* __restrict__ deg, int* __restrict__ bsum) {
    __shared__ int red[256];
    int base = blockIdx.x * 1024;
    int tid = threadIdx.x;
    int s = 0;
    for (int q = 0; q < 4; ++q) {
        int idx = base + tid * 4 + q;
        if (idx < N_NODES) s += deg[idx];
    }
    red[tid] = s; __syncthreads();
    for (int off = 128; off > 0; off >>= 1) {
        if (tid < off) red[tid] += red[tid + off];
        __syncthreads();
    }
    if (tid == 0) bsum[blockIdx.x] = red[0];
}

__global__ void k_scan2(int* __restrict__ bsum, int nb, int* __restrict__ rowstart) {
    if (threadIdx.x == 0) {
        int run = 0;
        for (int i = 0; i < nb; ++i) { int t = bsum[i]; bsum[i] = run; run += t; }
        rowstart[N_NODES] = run;   // == E
    }
}

__global__ void k_scan3(const int* __restrict__ deg, const int* __restrict__ bsum,
                        int* __restrict__ rowstart, int* __restrict__ cursor,
                        float* __restrict__ dinv) {
    __shared__ int tsum[256];
    int tid = threadIdx.x;
    int base = blockIdx.x * 1024;
    int v[4]; int tot = 0;
    for (int q = 0; q < 4; ++q) {
        int idx = base + tid * 4 + q;
        v[q] = (idx < N_NODES) ? deg[idx] : 0;
        tot += v[q];
    }
    tsum[tid] = tot; __syncthreads();
    for (int off = 1; off < 256; off <<= 1) {
        int t = (tid >= off) ? tsum[tid - off] : 0;
        __syncthreads();
        tsum[tid] += t;
        __syncthreads();
    }
    int run = bsum[blockIdx.x] + tsum[tid] - tot;
    for (int q = 0; q < 4; ++q) {
        int idx = base + tid * 4 + q;
        if (idx < N_NODES) {
            rowstart[idx] = run;
            cursor[idx]   = run;
            dinv[idx]     = rsqrtf(fmaxf((float)v[q], 1.0f));
            run += v[q];
        }
    }
}

__global__ void k_fill(const int* __restrict__ src, const int* __restrict__ dst,
                       int* __restrict__ cursor, int* __restrict__ csrc) {
    int e = blockIdx.x * blockDim.x + threadIdx.x;
    int p = atomicAdd(&cursor[dst[e]], 1);
    csrc[p] = src[e];
}

// ---------------- convert x -> hi/lo bf16 ----------------
__global__ void k_convert(const float* __restrict__ x,
                          ushort* __restrict__ Xh, ushort* __restrict__ Xl) {
    int i = blockIdx.x * 256 + threadIdx.x;     // one per 4 floats; 3.2M threads
    float4 v = ((const float4*)x)[i];
    unsigned h0 = bf16rnd(v.x), h1 = bf16rnd(v.y), h2 = bf16rnd(v.z), h3 = bf16rnd(v.w);
    float l0 = v.x - __uint_as_float(h0 << 16);
    float l1 = v.y - __uint_as_float(h1 << 16);
    float l2 = v.z - __uint_as_float(h2 << 16);
    float l3 = v.w - __uint_as_float(h3 << 16);
    uint2 ho; ho.x = h0 | (h1 << 16); ho.y = h2 | (h3 << 16);
    uint2 lo; lo.x = bf16rnd(l0) | (bf16rnd(l1) << 16); lo.y = bf16rnd(l2) | (bf16rnd(l3) << 16);
    ((uint2*)Xh)[i] = ho;
    ((uint2*)Xl)[i] = lo;
}

// ---------------- pack W (256x128) into MFMA B-fragment layout, hi/lo ----------------
// layout index: (((c*8 + kb)*64 + lane)*8 + j), value = W[(kb*32 + (lane>>4)*8 + j)*128 + c*16 + (lane&15)]
__global__ void k_packW(const float* __restrict__ W,
                        ushort* __restrict__ Wh, ushort* __restrict__ Wl) {
    int idx = blockIdx.x * 256 + threadIdx.x;   // 0..32767
    int j = idx & 7, l = (idx >> 3) & 63, kb = (idx >> 9) & 7, c = idx >> 12;
    int k = kb * 32 + (l >> 4) * 8 + j;
    int col = c * 16 + (l & 15);
    float w = W[k * 128 + col];
    unsigned h = bf16rnd(w);
    float rem = w - __uint_as_float(h << 16);
    Wh[idx] = (ushort)h;
    Wl[idx] = (ushort)bf16rnd(rem);
}

// ---------------- gather SpMM on hi/lo bf16: T = -dinv[n] * sum X[src]*dinv[src] -----
__global__ __launch_bounds__(256) void k_gather(
    const ushort* __restrict__ Ah, const ushort* __restrict__ Al,
    const float* __restrict__ dinv,
    const int* __restrict__ rowstart, const int* __restrict__ csrc,
    ushort* __restrict__ Th, ushort* __restrict__ Tl) {
    int tid = threadIdx.x;
    int c = tid & 31;          // 4-col group 0..31
    int i = tid >> 5;
    int n = blockIdx.x * 8 + i;
    int rs = rowstart[n], re = rowstart[n + 1];
    const uint2* Ah2 = (const uint2*)Ah;
    const uint2* Al2 = (const uint2*)Al;
    float a0 = 0.f, a1 = 0.f, a2 = 0.f, a3 = 0.f;
    for (int e = rs; e < re; ++e) {
        int s = csrc[e];
        float dv = dinv[s];
        uint2 h = Ah2[s * 32 + c];
        uint2 l = Al2[s * 32 + c];
        float f0 = __uint_as_float(h.x << 16)        + __uint_as_float(l.x << 16);
        float f1 = __uint_as_float(h.x & 0xffff0000u) + __uint_as_float(l.x & 0xffff0000u);
        float f2 = __uint_as_float(h.y << 16)        + __uint_as_float(l.y << 16);
        float f3 = __uint_as_float(h.y & 0xffff0000u) + __uint_as_float(l.y & 0xffff0000u);
        a0 = fmaf(f0, dv, a0); a1 = fmaf(f1, dv, a1);
        a2 = fmaf(f2, dv, a2); a3 = fmaf(f3, dv, a3);
    }
    float dn = -dinv[n];
    a0 *= dn; a1 *= dn; a2 *= dn; a3 *= dn;
    unsigned h0 = bf16rnd(a0), h1 = bf16rnd(a1), h2 = bf16rnd(a2), h3 = bf16rnd(a3);
    uint2 ho; ho.x = h0 | (h1 << 16); ho.y = h2 | (h3 << 16);
    float l0 = a0 - __uint_as_float(h0 << 16);
    float l1 = a1 - __uint_as_float(h1 << 16);
    float l2 = a2 - __uint_as_float(h2 << 16);
    float l3 = a3 - __uint_as_float(h3 << 16);
    uint2 lo; lo.x = bf16rnd(l0) | (bf16rnd(l1) << 16); lo.y = bf16rnd(l2) | (bf16rnd(l3) << 16);
    ((uint2*)Th)[n * 32 + c] = ho;
    ((uint2*)Tl)[n * 32 + c] = lo;
}

// ---------------- MFMA GEMM: OUT = relu([A0, A1] @ W + b) -----------------------
// split-bf16: 3 MFMAs per k-step (hh, hl, lh). mode 0: write hi/lo bf16 OUT.
// mode 1: fused segment-max into hg (each wave's 16 rows lie in one graph; 2000 = 125*16).
__global__ __launch_bounds__(256) void k_gemm_mfma(
    const ushort* __restrict__ A0h, const ushort* __restrict__ A0l,
    const ushort* __restrict__ A1h, const ushort* __restrict__ A1l,
    const ushort* __restrict__ Wh,  const ushort* __restrict__ Wl,
    const float* __restrict__ bias,
    ushort* __restrict__ Oh, ushort* __restrict__ Ol,
    float* __restrict__ hg, int mode) {
    int tid = threadIdx.x;
    int lane = tid & 63, wave = tid >> 6;
    int wrow = (blockIdx.x * 4 + wave) * 16;
    if (wrow >= N_NODES) return;
    int m = lane & 15, quad = lane >> 4;
    int row = wrow + m;

    f32x4 acc[8];
#pragma unroll
    for (int c = 0; c < 8; ++c) { acc[c][0] = 0.f; acc[c][1] = 0.f; acc[c][2] = 0.f; acc[c][3] = 0.f; }

#pragma unroll
    for (int kb = 0; kb < 8; ++kb) {
        const ushort* ph = (kb < 4) ? A0h : A1h;
        const ushort* pl = (kb < 4) ? A0l : A1l;
        int ko = (kb & 3) * 32 + quad * 8;
        short8 a_h = *reinterpret_cast<const short8*>(ph + row * FEAT + ko);
        short8 a_l = *reinterpret_cast<const short8*>(pl + row * FEAT + ko);
#pragma unroll
        for (int c = 0; c < 8; ++c) {
            int boff = ((c * 8 + kb) * 64 + lane) * 8;
            short8 b_h = *reinterpret_cast<const short8*>(Wh + boff);
            short8 b_l = *reinterpret_cast<const short8*>(Wl + boff);
            acc[c] = __builtin_amdgcn_mfma_f32_16x16x32_bf16(a_h, b_h, acc[c], 0, 0, 0);
            acc[c] = __builtin_amdgcn_mfma_f32_16x16x32_bf16(a_h, b_l, acc[c], 0, 0, 0);
            acc[c] = __builtin_amdgcn_mfma_f32_16x16x32_bf16(a_l, b_h, acc[c], 0, 0, 0);
        }
    }

    if (mode == 0) {
#pragma unroll
        for (int c = 0; c < 8; ++c) {
            int col = c * 16 + m;          // C/D: col = lane&15, row = quad*4 + reg
            float bb = bias[col];
#pragma unroll
            for (int r = 0; r < 4; ++r) {
                int orow = wrow + quad * 4 + r;
                float v = fmaxf(acc[c][r] + bb, 0.f);
                unsigned h = bf16rnd(v);
                float rem = v - __uint_as_float(h << 16);
                Oh[orow * FEAT + col] = (ushort)h;
                Ol[orow * FEAT + col] = (ushort)bf16rnd(rem);
            }
        }
    } else {
        int g = wrow / GSIZE;              // wave-uniform
#pragma unroll
        for (int c = 0; c < 8; ++c) {
            int col = c * 16 + m;
            float bb = bias[col];
            float vm = fmaxf(acc[c][0] + bb, 0.f);
            vm = fmaxf(vm, fmaxf(acc[c][1] + bb, 0.f));
            vm = fmaxf(vm, fmaxf(acc[c][2] + bb, 0.f));
            vm = fmaxf(vm, fmaxf(acc[c][3] + bb, 0.f));
            vm = fmaxf(vm, __shfl_xor(vm, 16));
            vm = fmaxf(vm, __shfl_xor(vm, 32));
            if (lane < 16)
                atomicMax((int*)&hg[g * FEAT + col], __float_as_int(vm));  // valid: vm >= 0, hg 0-init
        }
    }
}

// ---------------- classifier ----------------
__global__ void k_classify(const float* __restrict__ hg, const float* __restrict__ Wc,
                           const float* __restrict__ bc, float* __restrict__ out) {
    int g = blockIdx.x, t = threadIdx.x;
    if (t < NC) {
        float acc = bc[t];
        for (int j = 0; j < FEAT; ++j) acc += hg[g * FEAT + j] * Wc[j * NC + t];
        out[g * NC + t] = acc;
    }
}

extern "C" void kernel_launch(void* const* d_in, const int* in_sizes, int n_in,
                              void* d_out, int out_size, void* d_ws, size_t ws_size,
                              hipStream_t stream) {
    const float* x   = (const float*)d_in[0];
    const float* W1  = (const float*)d_in[1];
    const float* b1  = (const float*)d_in[2];
    const float* W2  = (const float*)d_in[3];
    const float* b2  = (const float*)d_in[4];
    const float* Wc  = (const float*)d_in[5];
    const float* bc  = (const float*)d_in[6];
    const int*   src = (const int*)d_in[7];
    const int*   dst = (const int*)d_in[8];
    float* out = (float*)d_out;

    char* ws = (char*)d_ws;
    size_t off = 0;
    auto alloc = [&](size_t bytes) { char* p = ws + off; off += (bytes + 255) & ~(size_t)255; return p; };
    int*    deg      = (int*)   alloc(N_NODES * 4);
    float*  dinv     = (float*) alloc(N_NODES * 4);
    int*    rowstart = (int*)   alloc((N_NODES + 1) * 4);
    int*    cursor   = (int*)   alloc(N_NODES * 4);
    int*    bsum     = (int*)   alloc(256 * 4);
    float*  hg       = (float*) alloc(NB * FEAT * 4);
    int*    csrc     = (int*)   alloc((size_t)N_EDGES * 4);
    ushort* W1h      = (ushort*)alloc(256 * 128 * 2);
    ushort* W1l      = (ushort*)alloc(256 * 128 * 2);
    ushort* W2h      = (ushort*)alloc(256 * 128 * 2);
    ushort* W2l      = (ushort*)alloc(256 * 128 * 2);
    ushort* P1       = (ushort*)alloc((size_t)N_NODES * FEAT * 2);  // Xh -> Hh
    ushort* P2       = (ushort*)alloc((size_t)N_NODES * FEAT * 2);  // Xl -> Hl
    ushort* P3       = (ushort*)alloc((size_t)N_NODES * FEAT * 2);  // T1h -> T2h
    ushort* P4       = (ushort*)alloc((size_t)N_NODES * FEAT * 2);  // T1l -> T2l

    hipMemsetAsync(deg, 0, N_NODES * 4, stream);
    hipMemsetAsync(hg, 0, NB * FEAT * 4, stream);

    k_count<<<N_EDGES / 256, 256, 0, stream>>>(dst, deg);
    k_scan1<<<SCAN_BLOCKS, 256, 0, stream>>>(deg, bsum);
    k_scan2<<<1, 64, 0, stream>>>(bsum, SCAN_BLOCKS, rowstart);
    k_scan3<<<SCAN_BLOCKS, 256, 0, stream>>>(deg, bsum, rowstart, cursor, dinv);
    k_fill<<<N_EDGES / 256, 256, 0, stream>>>(src, dst, cursor, csrc);

    k_convert<<<(N_NODES * FEAT / 4) / 256, 256, 0, stream>>>(x, P1, P2);
    k_packW<<<128, 256, 0, stream>>>(W1, W1h, W1l);
    k_packW<<<128, 256, 0, stream>>>(W2, W2h, W2l);

    // layer 1
    k_gather<<<N_NODES / 8, 256, 0, stream>>>(P1, P2, dinv, rowstart, csrc, P3, P4);
    k_gemm_mfma<<<(6250 + 3) / 4, 256, 0, stream>>>(P1, P2, P3, P4, W1h, W1l, b1,
                                                    P1, P2, nullptr, 0);   // in-place per-row: safe
    // layer 2
    k_gather<<<N_NODES / 8, 256, 0, stream>>>(P1, P2, dinv, rowstart, csrc, P3, P4);
    k_gemm_mfma<<<(6250 + 3) / 4, 256, 0, stream>>>(P1, P2, P3, P4, W2h, W2l, b2,
                                                    nullptr, nullptr, hg, 1); // fused segmax

    k_classify<<<NB, 64, 0, stream>>>(hg, Wc, bc, out);
}

// Round 3
// 447.817 us; speedup vs baseline: 1.6986x; 1.4309x over previous
//
#include <hip/hip_runtime.h>

#define N_NODES 100000
#define N_EDGES 1600000
#define NB      50
#define GSIZE   2000
#define FEAT    128
#define NC      10
#define SCAN_BLOCKS 98     // ceil(100000/1024)
#define BCAP    40960      // per-graph bucket capacity (mean 32000, sd ~177 -> 50 sigma)
#define CHUNK   2048       // edges per binA block
#define NBLK_A  782        // ceil(E / CHUNK)
#define STAGE_CAP 12288    // binB stage (span mean 8000, sd ~89)

using short8 = __attribute__((ext_vector_type(8))) short;
using f32x4  = __attribute__((ext_vector_type(4))) float;

__device__ __forceinline__ unsigned bf16rnd(float f) {
    unsigned u = __float_as_uint(f);
    return (u + 0x7fffu + ((u >> 16) & 1u)) >> 16;   // RNE bf16 bits
}

// ---------------- phase A: bin edges into 50 per-graph buckets (LDS-staged) --------
__global__ __launch_bounds__(256) void k_binA(
    const int* __restrict__ src, const int* __restrict__ dst,
    unsigned* __restrict__ gbuf, int* __restrict__ gcur) {
    __shared__ int cnt[NB];
    __shared__ int base[NB];
    __shared__ int gbase[NB];
    __shared__ unsigned stage[CHUNK];
    __shared__ unsigned char bslot[CHUNK];
    __shared__ int total_s;
    int tid = threadIdx.x;
    int e0 = blockIdx.x * CHUNK;
    for (int i = tid; i < NB; i += 256) cnt[i] = 0;
    __syncthreads();

    unsigned pv[8]; int pb[8], pr[8]; int nv = 0;
#pragma unroll
    for (int q = 0; q < 8; ++q) {
        int e = e0 + q * 256 + tid;
        pb[q] = -1;
        if (e < N_EDGES) {
            int d = dst[e];
            int g = d / 2000;            // compiler magic-mul
            pv[q] = ((unsigned)src[e] << 11) | (unsigned)(d - g * 2000);
            pb[q] = g;
            pr[q] = atomicAdd(&cnt[g], 1);
            ++nv;
        }
    }
    __syncthreads();
    if (tid == 0) {
        int run = 0;
        for (int b = 0; b < NB; ++b) { base[b] = run; run += cnt[b]; }
        total_s = run;
    }
    __syncthreads();
#pragma unroll
    for (int q = 0; q < 8; ++q) {
        if (pb[q] >= 0) {
            int s = base[pb[q]] + pr[q];
            stage[s] = pv[q];
            bslot[s] = (unsigned char)pb[q];
        }
    }
    if (tid < NB) gbase[tid] = atomicAdd(&gcur[tid], cnt[tid]);
    __syncthreads();
    int total = total_s;
    for (int s = tid; s < total; s += 256) {
        int b = bslot[s];
        gbuf[(size_t)b * BCAP + gbase[b] + (s - base[b])] = stage[s];
    }
}

// ---------------- per-node degree from buckets (LDS histogram, no global atomics) --
__global__ __launch_bounds__(256) void k_hist(
    const unsigned* __restrict__ gbuf, const int* __restrict__ gcur,
    int* __restrict__ deg) {
    __shared__ int hist[GSIZE];
    int g = blockIdx.x, tid = threadIdx.x;
    for (int i = tid; i < GSIZE; i += 256) hist[i] = 0;
    __syncthreads();
    int n = gcur[g];
    const unsigned* bp = gbuf + (size_t)g * BCAP;
    for (int i = tid; i < n; i += 256)
        atomicAdd(&hist[bp[i] & 2047u], 1);
    __syncthreads();
    for (int i = tid; i < GSIZE; i += 256)
        deg[g * GSIZE + i] = hist[i];
}

// ---------------- scan (3-phase) ----------------
__global__ void k_scan1(const int* __restrict__ deg, int* __restrict__ bsum) {
    __shared__ int red[256];
    int base = blockIdx.x * 1024;
    int tid = threadIdx.x;
    int s = 0;
    for (int q = 0; q < 4; ++q) {
        int idx = base + tid * 4 + q;
        if (idx < N_NODES) s += deg[idx];
    }
    red[tid] = s; __syncthreads();
    for (int off = 128; off > 0; off >>= 1) {
        if (tid < off) red[tid] += red[tid + off];
        __syncthreads();
    }
    if (tid == 0) bsum[blockIdx.x] = red[0];
}

__global__ void k_scan2(int* __restrict__ bsum, int nb, int* __restrict__ rowstart) {
    if (threadIdx.x == 0) {
        int run = 0;
        for (int i = 0; i < nb; ++i) { int t = bsum[i]; bsum[i] = run; run += t; }
        rowstart[N_NODES] = run;   // == E
    }
}

__global__ void k_scan3(const int* __restrict__ deg, const int* __restrict__ bsum,
                        int* __restrict__ rowstart, float* __restrict__ dinv) {
    __shared__ int tsum[256];
    int tid = threadIdx.x;
    int base = blockIdx.x * 1024;
    int v[4]; int tot = 0;
    for (int q = 0; q < 4; ++q) {
        int idx = base + tid * 4 + q;
        v[q] = (idx < N_NODES) ? deg[idx] : 0;
        tot += v[q];
    }
    tsum[tid] = tot; __syncthreads();
    for (int off = 1; off < 256; off <<= 1) {
        int t = (tid >= off) ? tsum[tid - off] : 0;
        __syncthreads();
        tsum[tid] += t;
        __syncthreads();
    }
    int run = bsum[blockIdx.x] + tsum[tid] - tot;
    for (int q = 0; q < 4; ++q) {
        int idx = base + tid * 4 + q;
        if (idx < N_NODES) {
            rowstart[idx] = run;
            dinv[idx]     = rsqrtf(fmaxf((float)v[q], 1.0f));
            run += v[q];
        }
    }
}

// ---------------- phase B: build csrc in LDS, write coalesced ----------------------
// 4 blocks per graph, each owns 500 consecutive dst nodes.
__global__ __launch_bounds__(256) void k_binB(
    const unsigned* __restrict__ gbuf, const int* __restrict__ gcur,
    const int* __restrict__ rowstart, int* __restrict__ csrc) {
    __shared__ int lcur[500];
    __shared__ int stage[STAGE_CAP];
    int g = blockIdx.x >> 2, q = blockIdx.x & 3;
    int tid = threadIdx.x;
    int n0 = g * GSIZE + q * 500;
    int n0l = q * 500;
    int span0 = rowstart[n0];
    int span  = rowstart[n0 + 500] - span0;
    for (int i = tid; i < 500; i += 256) lcur[i] = rowstart[n0 + i] - span0;
    __syncthreads();
    int n = gcur[g];
    const unsigned* bp = gbuf + (size_t)g * BCAP;
    for (int i = tid; i < n; i += 256) {
        unsigned v = bp[i];
        unsigned d = (v & 2047u) - (unsigned)n0l;
        if (d < 500u) {
            int p = atomicAdd(&lcur[d], 1);
            stage[p] = (int)(v >> 11);
        }
    }
    __syncthreads();
    for (int s = tid; s < span; s += 256)
        csrc[span0 + s] = stage[s];
}

// ---------------- convert x -> Xh (bf16) and Yh = bf16(dinv*x) ---------------------
__global__ __launch_bounds__(256) void k_convert(const float* __restrict__ x,
                          const float* __restrict__ dinv,
                          ushort* __restrict__ Xh, ushort* __restrict__ Yh) {
    int i = blockIdx.x * 256 + threadIdx.x;     // one per 4 floats
    int node = i >> 5;                          // 32 float4 per row
    float dv = dinv[node];
    float4 v = ((const float4*)x)[i];
    uint2 ho;
    ho.x = bf16rnd(v.x) | (bf16rnd(v.y) << 16);
    ho.y = bf16rnd(v.z) | (bf16rnd(v.w) << 16);
    uint2 yo;
    yo.x = bf16rnd(v.x * dv) | (bf16rnd(v.y * dv) << 16);
    yo.y = bf16rnd(v.z * dv) | (bf16rnd(v.w * dv) << 16);
    ((uint2*)Xh)[i] = ho;
    ((uint2*)Yh)[i] = yo;
}

// ---------------- pack W (256x128) into MFMA B-fragment layout, hi/lo --------------
__global__ void k_packW(const float* __restrict__ W,
                        ushort* __restrict__ Wh, ushort* __restrict__ Wl) {
    int idx = blockIdx.x * 256 + threadIdx.x;   // 0..32767
    int j = idx & 7, l = (idx >> 3) & 63, kb = (idx >> 9) & 7, c = idx >> 12;
    int k = kb * 32 + (l >> 4) * 8 + j;
    int col = c * 16 + (l & 15);
    float w = W[k * 128 + col];
    unsigned h = bf16rnd(w);
    float rem = w - __uint_as_float(h << 16);
    Wh[idx] = (ushort)h;
    Wl[idx] = (ushort)bf16rnd(rem);
}

// ---------------- gather: T[n] = bf16( -dinv[n] * sum_e Yh[csrc[e]] ) --------------
__global__ __launch_bounds__(256) void k_gather(
    const ushort* __restrict__ Yh, const float* __restrict__ dinv,
    const int* __restrict__ rowstart, const int* __restrict__ csrc,
    ushort* __restrict__ Th) {
    int tid = threadIdx.x;
    int c = tid & 31;          // 4-col group 0..31
    int i = tid >> 5;
    int n = blockIdx.x * 8 + i;
    int rs = rowstart[n], re = rowstart[n + 1];
    const uint2* Y2 = (const uint2*)Yh;
    float a0 = 0.f, a1 = 0.f, a2 = 0.f, a3 = 0.f;
    float b0 = 0.f, b1 = 0.f, b2 = 0.f, b3 = 0.f;
    int e = rs;
    for (; e + 1 < re; e += 2) {
        int s0 = csrc[e], s1 = csrc[e + 1];
        uint2 h0 = Y2[s0 * 32 + c];
        uint2 h1 = Y2[s1 * 32 + c];
        a0 += __uint_as_float(h0.x << 16);         a1 += __uint_as_float(h0.x & 0xffff0000u);
        a2 += __uint_as_float(h0.y << 16);         a3 += __uint_as_float(h0.y & 0xffff0000u);
        b0 += __uint_as_float(h1.x << 16);         b1 += __uint_as_float(h1.x & 0xffff0000u);
        b2 += __uint_as_float(h1.y << 16);         b3 += __uint_as_float(h1.y & 0xffff0000u);
    }
    if (e < re) {
        int s0 = csrc[e];
        uint2 h0 = Y2[s0 * 32 + c];
        a0 += __uint_as_float(h0.x << 16);         a1 += __uint_as_float(h0.x & 0xffff0000u);
        a2 += __uint_as_float(h0.y << 16);         a3 += __uint_as_float(h0.y & 0xffff0000u);
    }
    a0 += b0; a1 += b1; a2 += b2; a3 += b3;
    float dn = -dinv[n];
    uint2 o;
    o.x = bf16rnd(a0 * dn) | (bf16rnd(a1 * dn) << 16);
    o.y = bf16rnd(a2 * dn) | (bf16rnd(a3 * dn) << 16);
    ((uint2*)Th)[n * 32 + c] = o;
}

// ---------------- MFMA GEMM: OUT = relu([A0, A1] @ W + b) --------------------------
// A in bf16 (hi only); W split hi/lo -> 2 MFMAs per k-step.
// mode 0: write Hh = bf16(out) and Yh = bf16(out * dinv[row])  (layer-2 prescale fused)
// mode 1: fused segment-max into hg (wave's 16 rows lie in one graph; 2000 = 125*16).
__global__ __launch_bounds__(256) void k_gemm_mfma(
    const ushort* __restrict__ A0h, const ushort* __restrict__ A1h,
    const ushort* __restrict__ Wh,  const ushort* __restrict__ Wl,
    const float* __restrict__ bias, const float* __restrict__ dinv,
    ushort* __restrict__ Oh, ushort* __restrict__ Oy,
    float* __restrict__ hg, int mode) {
    int tid = threadIdx.x;
    int lane = tid & 63, wave = tid >> 6;
    int wrow = (blockIdx.x * 4 + wave) * 16;
    if (wrow >= N_NODES) return;
    int m = lane & 15, quad = lane >> 4;
    int row = wrow + m;

    f32x4 acc[8];
#pragma unroll
    for (int c = 0; c < 8; ++c) { acc[c][0] = 0.f; acc[c][1] = 0.f; acc[c][2] = 0.f; acc[c][3] = 0.f; }

#pragma unroll
    for (int kb = 0; kb < 8; ++kb) {
        const ushort* ph = (kb < 4) ? A0h : A1h;
        int ko = (kb & 3) * 32 + quad * 8;
        short8 a_h = *reinterpret_cast<const short8*>(ph + row * FEAT + ko);
#pragma unroll
        for (int c = 0; c < 8; ++c) {
            int boff = ((c * 8 + kb) * 64 + lane) * 8;
            short8 b_h = *reinterpret_cast<const short8*>(Wh + boff);
            short8 b_l = *reinterpret_cast<const short8*>(Wl + boff);
            acc[c] = __builtin_amdgcn_mfma_f32_16x16x32_bf16(a_h, b_h, acc[c], 0, 0, 0);
            acc[c] = __builtin_amdgcn_mfma_f32_16x16x32_bf16(a_h, b_l, acc[c], 0, 0, 0);
        }
    }

    if (mode == 0) {
#pragma unroll
        for (int r = 0; r < 4; ++r) {
            int orow = wrow + quad * 4 + r;     // C/D: col = lane&15, row = quad*4 + reg
            float dv = dinv[orow];
#pragma unroll
            for (int c = 0; c < 8; ++c) {
                int col = c * 16 + m;
                float v = fmaxf(acc[c][r] + bias[col], 0.f);
                Oh[orow * FEAT + col] = (ushort)bf16rnd(v);
                Oy[orow * FEAT + col] = (ushort)bf16rnd(v * dv);
            }
        }
    } else {
        int g = wrow / GSIZE;              // wave-uniform
#pragma unroll
        for (int c = 0; c < 8; ++c) {
            int col = c * 16 + m;
            float bb = bias[col];
            float vm = fmaxf(acc[c][0] + bb, 0.f);
            vm = fmaxf(vm, fmaxf(acc[c][1] + bb, 0.f));
            vm = fmaxf(vm, fmaxf(acc[c][2] + bb, 0.f));
            vm = fmaxf(vm, fmaxf(acc[c][3] + bb, 0.f));
            vm = fmaxf(vm, __shfl_xor(vm, 16));
            vm = fmaxf(vm, __shfl_xor(vm, 32));
            if (lane < 16)
                atomicMax((int*)&hg[g * FEAT + col], __float_as_int(vm));  // vm >= 0, hg 0-init
        }
    }
}

// ---------------- classifier ----------------
__global__ void k_classify(const float* __restrict__ hg, const float* __restrict__ Wc,
                           const float* __restrict__ bc, float* __restrict__ out) {
    int g = blockIdx.x, t = threadIdx.x;
    if (t < NC) {
        float acc = bc[t];
        for (int j = 0; j < FEAT; ++j) acc += hg[g * FEAT + j] * Wc[j * NC + t];
        out[g * NC + t] = acc;
    }
}

extern "C" void kernel_launch(void* const* d_in, const int* in_sizes, int n_in,
                              void* d_out, int out_size, void* d_ws, size_t ws_size,
                              hipStream_t stream) {
    const float* x   = (const float*)d_in[0];
    const float* W1  = (const float*)d_in[1];
    const float* b1  = (const float*)d_in[2];
    const float* W2  = (const float*)d_in[3];
    const float* b2  = (const float*)d_in[4];
    const float* Wc  = (const float*)d_in[5];
    const float* bc  = (const float*)d_in[6];
    const int*   src = (const int*)d_in[7];
    const int*   dst = (const int*)d_in[8];
    float* out = (float*)d_out;

    char* ws = (char*)d_ws;
    size_t off = 0;
    auto alloc = [&](size_t bytes) { char* p = ws + off; off += (bytes + 255) & ~(size_t)255; return p; };
    int*      deg      = (int*)     alloc(N_NODES * 4);
    float*    dinv     = (float*)   alloc(N_NODES * 4);
    int*      rowstart = (int*)     alloc((N_NODES + 1) * 4);
    int*      bsum     = (int*)     alloc(256 * 4);
    int*      gcur     = (int*)     alloc(NB * 4);
    float*    hg       = (float*)   alloc(NB * FEAT * 4);
    unsigned* gbuf     = (unsigned*)alloc((size_t)NB * BCAP * 4);
    int*      csrc     = (int*)     alloc((size_t)N_EDGES * 4);
    ushort*   W1h      = (ushort*)  alloc(256 * 128 * 2);
    ushort*   W1l      = (ushort*)  alloc(256 * 128 * 2);
    ushort*   W2h      = (ushort*)  alloc(256 * 128 * 2);
    ushort*   W2l      = (ushort*)  alloc(256 * 128 * 2);
    ushort*   Xh       = (ushort*)  alloc((size_t)N_NODES * FEAT * 2);  // Xh -> Hh (in-place)
    ushort*   Yh       = (ushort*)  alloc((size_t)N_NODES * FEAT * 2);  // dinv*x -> dinv*h
    ushort*   Th       = (ushort*)  alloc((size_t)N_NODES * FEAT * 2);  // T1 -> T2

    hipMemsetAsync(gcur, 0, NB * 4, stream);
    hipMemsetAsync(hg, 0, NB * FEAT * 4, stream);

    // CSR build (two-phase counting sort; no global scatter amplification)
    k_binA<<<NBLK_A, 256, 0, stream>>>(src, dst, gbuf, gcur);
    k_hist<<<NB, 256, 0, stream>>>(gbuf, gcur, deg);
    k_scan1<<<SCAN_BLOCKS, 256, 0, stream>>>(deg, bsum);
    k_scan2<<<1, 64, 0, stream>>>(bsum, SCAN_BLOCKS, rowstart);
    k_scan3<<<SCAN_BLOCKS, 256, 0, stream>>>(deg, bsum, rowstart, dinv);
    k_binB<<<NB * 4, 256, 0, stream>>>(gbuf, gcur, rowstart, csrc);

    k_convert<<<(N_NODES * FEAT / 4) / 256, 256, 0, stream>>>(x, dinv, Xh, Yh);
    k_packW<<<128, 256, 0, stream>>>(W1, W1h, W1l);
    k_packW<<<128, 256, 0, stream>>>(W2, W2h, W2l);

    // layer 1 (gemm writes Hh into Xh and dinv*h into Yh, in-place per-row: safe)
    k_gather<<<N_NODES / 8, 256, 0, stream>>>(Yh, dinv, rowstart, csrc, Th);
    k_gemm_mfma<<<(6250 + 3) / 4, 256, 0, stream>>>(Xh, Th, W1h, W1l, b1, dinv,
                                                    Xh, Yh, nullptr, 0);
    // layer 2 (fused segmax)
    k_gather<<<N_NODES / 8, 256, 0, stream>>>(Yh, dinv, rowstart, csrc, Th);
    k_gemm_mfma<<<(6250 + 3) / 4, 256, 0, stream>>>(Xh, Th, W2h, W2l, b2, dinv,
                                                    nullptr, nullptr, hg, 1);

    k_classify<<<NB, 64, 0, stream>>>(hg, Wc, bc, out);
}

// Round 5
// 367.938 us; speedup vs baseline: 2.0674x; 1.2171x over previous
//
#include <hip/hip_runtime.h>

#define N_NODES 100000
#define N_EDGES 1600000
#define NB      50
#define GSIZE   2000
#define FEAT    128
#define NC      10
#define BCAP    40960      // per-graph bucket capacity (mean 32000, sd ~177)
#define CHUNK   2048       // edges per binA block
#define NBLK_A  782        // ceil(E / CHUNK)
#define STAGE_CAP 12288    // binB stage (span mean 8000, sd ~89)

using short8 = __attribute__((ext_vector_type(8))) short;
using f32x4  = __attribute__((ext_vector_type(4))) float;

__device__ __forceinline__ unsigned bf16rnd(float f) {
    unsigned u = __float_as_uint(f);
    return (u + 0x7fffu + ((u >> 16) & 1u)) >> 16;   // RNE bf16 bits
}
__device__ __forceinline__ float blo(unsigned w) { return __uint_as_float(w << 16); }
__device__ __forceinline__ float bhi(unsigned w) { return __uint_as_float(w & 0xffff0000u); }

// XCD-pinned graph mapping: assumes XCD = blockIdx % 8 round-robin.
// XCD k owns graphs {k, k+8, ..., k+40} plus graph 48 (k=0) / 49 (k=1).
// Returns -1 for idle pad blocks.
__device__ __forceinline__ int graph_of(int k, int gi) {
    if (gi < 6) return k + 8 * gi;
    return (k < 2) ? (48 + k) : -1;
}

// ---------------- phase A: bin edges into 50 per-graph buckets (LDS-staged) --------
__global__ __launch_bounds__(256) void k_binA(
    const int* __restrict__ src, const int* __restrict__ dst,
    unsigned* __restrict__ gbuf, int* __restrict__ gcur) {
    __shared__ int cnt[NB];
    __shared__ int base[NB];
    __shared__ int gbase[NB];
    __shared__ unsigned stage[CHUNK];
    __shared__ unsigned char bslot[CHUNK];
    __shared__ int total_s;
    int tid = threadIdx.x;
    int e0 = blockIdx.x * CHUNK;
    for (int i = tid; i < NB; i += 256) cnt[i] = 0;
    __syncthreads();

    unsigned pv[8]; int pb[8], pr[8];
#pragma unroll
    for (int q = 0; q < 8; ++q) {
        int e = e0 + q * 256 + tid;
        pb[q] = -1;
        if (e < N_EDGES) {
            int d = dst[e];
            int g = d / 2000;
            pv[q] = ((unsigned)src[e] << 11) | (unsigned)(d - g * 2000);
            pb[q] = g;
            pr[q] = atomicAdd(&cnt[g], 1);
        }
    }
    __syncthreads();
    if (tid == 0) {
        int run = 0;
        for (int b = 0; b < NB; ++b) { base[b] = run; run += cnt[b]; }
        total_s = run;
    }
    __syncthreads();
#pragma unroll
    for (int q = 0; q < 8; ++q) {
        if (pb[q] >= 0) {
            int s = base[pb[q]] + pr[q];
            stage[s] = pv[q];
            bslot[s] = (unsigned char)pb[q];
        }
    }
    if (tid < NB) gbase[tid] = atomicAdd(&gcur[tid], cnt[tid]);
    __syncthreads();
    int total = total_s;
    for (int s = tid; s < total; s += 256) {
        int b = bslot[s];
        gbuf[(size_t)b * BCAP + gbase[b] + (s - base[b])] = stage[s];
    }
}

// ---------------- per-graph: hist + scan -> rowstart, dinv, sdeg -------------------
__global__ __launch_bounds__(256) void k_prep(
    const unsigned* __restrict__ gbuf, const int* __restrict__ gcur,
    int* __restrict__ rowstart, float* __restrict__ dinv, float* __restrict__ sdeg) {
    __shared__ int hist[GSIZE];
    __shared__ int tsum[256];
    __shared__ int goff_s;
    int B = blockIdx.x; int k = B & 7, gi = B >> 3;
    int g = graph_of(k, gi);
    if (g < 0) return;
    int tid = threadIdx.x;
    for (int i = tid; i < GSIZE; i += 256) hist[i] = 0;
    if (tid == 0) { int run = 0; for (int i = 0; i < g; ++i) run += gcur[i]; goff_s = run; }
    __syncthreads();
    int n = gcur[g];
    const unsigned* bp = gbuf + (size_t)g * BCAP;
    for (int i = tid; i < n; i += 256) atomicAdd(&hist[bp[i] & 2047u], 1);
    __syncthreads();
    int base = tid * 8;
    int v[8]; int loc = 0;
#pragma unroll
    for (int q = 0; q < 8; ++q) {
        int idx = base + q;
        v[q] = (idx < GSIZE) ? hist[idx] : 0;
        loc += v[q];
    }
    tsum[tid] = loc; __syncthreads();
    for (int off = 1; off < 256; off <<= 1) {
        int t = (tid >= off) ? tsum[tid - off] : 0;
        __syncthreads(); tsum[tid] += t; __syncthreads();
    }
    int run = goff_s + tsum[tid] - loc;
#pragma unroll
    for (int q = 0; q < 8; ++q) {
        int idx = base + q;
        if (idx < GSIZE) {
            int node = g * GSIZE + idx;
            rowstart[node] = run;
            float d = fmaxf((float)v[q], 1.f);
            dinv[node] = rsqrtf(d);
            sdeg[node] = sqrtf(d);
            run += v[q];
        }
    }
    if (tid == 0) rowstart[g * GSIZE + GSIZE] = goff_s + n;  // == next graph's start
}

// ---------------- phase B: build csrc in LDS, write coalesced ----------------------
__global__ __launch_bounds__(256) void k_binB(
    const unsigned* __restrict__ gbuf, const int* __restrict__ gcur,
    const int* __restrict__ rowstart, int* __restrict__ csrc) {
    __shared__ int lcur[500];
    __shared__ int stage[STAGE_CAP];
    int B = blockIdx.x; int k = B & 7, j = B >> 3;
    int gi = j >> 2, q = j & 3;
    int g = graph_of(k, gi);
    if (g < 0) return;
    int tid = threadIdx.x;
    int n0 = g * GSIZE + q * 500;
    int n0l = q * 500;
    int span0 = rowstart[n0];
    int span  = rowstart[n0 + 500] - span0;
    for (int i = tid; i < 500; i += 256) lcur[i] = rowstart[n0 + i] - span0;
    __syncthreads();
    int n = gcur[g];
    const unsigned* bp = gbuf + (size_t)g * BCAP;
    for (int i = tid; i < n; i += 256) {
        unsigned v = bp[i];
        unsigned d = (v & 2047u) - (unsigned)n0l;
        if (d < 500u) {
            int p = atomicAdd(&lcur[d], 1);
            stage[p] = (int)(v >> 11);
        }
    }
    __syncthreads();
    for (int s = tid; s < span; s += 256)
        csrc[span0 + s] = stage[s];
}

// ---------------- convert: Yh = bf16(dinv * x) (XCD-pinned per graph) --------------
__global__ __launch_bounds__(256) void k_convert(const float* __restrict__ x,
                          const float* __restrict__ dinv, ushort* __restrict__ Yh) {
    int B = blockIdx.x; int k = B & 7, j = B >> 3;
    int gi = j / 250, local = j % 250;
    int g = graph_of(k, gi);
    if (g < 0) return;
    int tid = threadIdx.x;
    int r = tid >> 5, c = tid & 31;
    int node = g * GSIZE + local * 8 + r;
    float dv = dinv[node];
    float4 v = ((const float4*)x)[node * 32 + c];
    uint2 yo;
    yo.x = bf16rnd(v.x * dv) | (bf16rnd(v.y * dv) << 16);
    yo.y = bf16rnd(v.z * dv) | (bf16rnd(v.w * dv) << 16);
    ((uint2*)Yh)[node * 32 + c] = yo;
}

// ---------------- pack W (256x128) into MFMA B-fragment layout, hi/lo --------------
__global__ void k_packW(const float* __restrict__ W,
                        ushort* __restrict__ Wh, ushort* __restrict__ Wl) {
    int idx = blockIdx.x * 256 + threadIdx.x;   // 0..32767
    int j = idx & 7, l = (idx >> 3) & 63, kb = (idx >> 9) & 7, c = idx >> 12;
    int k = kb * 32 + (l >> 4) * 8 + j;
    int col = c * 16 + (l & 15);
    float w = W[k * 128 + col];
    unsigned h = bf16rnd(w);
    float rem = w - __uint_as_float(h << 16);
    Wh[idx] = (ushort)h;
    Wl[idx] = (ushort)bf16rnd(rem);
}

// ---------------- gather: T[n] = bf16( -dinv[n] * sum_e Yh[csrc[e]] ) --------------
// XCD-pinned: 16 nodes/block, 16 lanes/node, 16B loads. Row = 16 uint4 (256 B).
__global__ __launch_bounds__(256) void k_gather(
    const ushort* __restrict__ Yh, const float* __restrict__ dinv,
    const int* __restrict__ rowstart, const int* __restrict__ csrc,
    ushort* __restrict__ Th) {
    int B = blockIdx.x; int k = B & 7, j = B >> 3;
    int gi = j / 125, local = j % 125;
    int g = graph_of(k, gi);
    if (g < 0) return;
    int tid = threadIdx.x;
    int c = tid & 15;          // 16B column group 0..15
    int i = tid >> 4;          // node 0..15
    int n = g * GSIZE + local * 16 + i;
    int rs = rowstart[n], re = rowstart[n + 1];
    const uint4* Y4 = (const uint4*)Yh;
    float a0=0.f,a1=0.f,a2=0.f,a3=0.f,a4=0.f,a5=0.f,a6=0.f,a7=0.f;
    float d0=0.f,d1=0.f,d2=0.f,d3=0.f,d4=0.f,d5=0.f,d6=0.f,d7=0.f;
    int e = rs;
    for (; e + 1 < re; e += 2) {
        int s0 = csrc[e], s1 = csrc[e + 1];
        uint4 u = Y4[s0 * 16 + c];
        uint4 w = Y4[s1 * 16 + c];
        a0 += blo(u.x); a1 += bhi(u.x); a2 += blo(u.y); a3 += bhi(u.y);
        a4 += blo(u.z); a5 += bhi(u.z); a6 += blo(u.w); a7 += bhi(u.w);
        d0 += blo(w.x); d1 += bhi(w.x); d2 += blo(w.y); d3 += bhi(w.y);
        d4 += blo(w.z); d5 += bhi(w.z); d6 += blo(w.w); d7 += bhi(w.w);
    }
    if (e < re) {
        uint4 u = Y4[csrc[e] * 16 + c];
        a0 += blo(u.x); a1 += bhi(u.x); a2 += blo(u.y); a3 += bhi(u.y);
        a4 += blo(u.z); a5 += bhi(u.z); a6 += blo(u.w); a7 += bhi(u.w);
    }
    a0+=d0; a1+=d1; a2+=d2; a3+=d3; a4+=d4; a5+=d5; a6+=d6; a7+=d7;
    float dn = -dinv[n];
    uint4 o;
    o.x = bf16rnd(a0 * dn) | (bf16rnd(a1 * dn) << 16);
    o.y = bf16rnd(a2 * dn) | (bf16rnd(a3 * dn) << 16);
    o.z = bf16rnd(a4 * dn) | (bf16rnd(a5 * dn) << 16);
    o.w = bf16rnd(a6 * dn) | (bf16rnd(a7 * dn) << 16);
    ((uint4*)Th)[n * 16 + c] = o;
}

// ---------------- MFMA GEMM: out = relu(sdeg_row*(Y@Wa) + T@Wb + b) ----------------
// A planes: Yh (k 0..127, rescaled by sdeg in epilogue -> H part), Th (k 128..255).
// W split hi/lo -> 2 MFMAs per k-step. XCD-pinned per graph.
// mode 0: Oy = bf16(out * dinv[row]).  mode 1: fused segment-max into hg.
__global__ __launch_bounds__(256) void k_gemm(
    const ushort* __restrict__ Yh, const ushort* __restrict__ Th,
    const ushort* __restrict__ Wh, const ushort* __restrict__ Wl,
    const float* __restrict__ bias, const float* __restrict__ dinv,
    const float* __restrict__ sdeg,
    ushort* __restrict__ Oy, float* __restrict__ hg, int mode) {
    int B = blockIdx.x; int k = B & 7, j = B >> 3;
    int gi = j >> 5, local = j & 31;
    int g = graph_of(k, gi);
    if (g < 0) return;
    int tid = threadIdx.x;
    int lane = tid & 63, wave = tid >> 6;
    int wl = local * 64 + wave * 16;
    if (wl >= GSIZE) return;                 // tail block: only wave 0 active
    int wrow = g * GSIZE + wl;
    int m = lane & 15, quad = lane >> 4;
    int row = wrow + m;

    f32x4 accA[8], accB[8];
#pragma unroll
    for (int c = 0; c < 8; ++c)
        for (int r = 0; r < 4; ++r) { accA[c][r] = 0.f; accB[c][r] = 0.f; }

#pragma unroll
    for (int kb = 0; kb < 4; ++kb) {
        int ko = kb * 32 + quad * 8;
        short8 aY = *reinterpret_cast<const short8*>(Yh + row * FEAT + ko);
        short8 aT = *reinterpret_cast<const short8*>(Th + row * FEAT + ko);
#pragma unroll
        for (int c = 0; c < 8; ++c) {
            int bo1 = ((c * 8 + kb) * 64 + lane) * 8;
            int bo2 = ((c * 8 + kb + 4) * 64 + lane) * 8;
            short8 b1h = *reinterpret_cast<const short8*>(Wh + bo1);
            short8 b1l = *reinterpret_cast<const short8*>(Wl + bo1);
            short8 b2h = *reinterpret_cast<const short8*>(Wh + bo2);
            short8 b2l = *reinterpret_cast<const short8*>(Wl + bo2);
            accA[c] = __builtin_amdgcn_mfma_f32_16x16x32_bf16(aY, b1h, accA[c], 0, 0, 0);
            accA[c] = __builtin_amdgcn_mfma_f32_16x16x32_bf16(aY, b1l, accA[c], 0, 0, 0);
            accB[c] = __builtin_amdgcn_mfma_f32_16x16x32_bf16(aT, b2h, accB[c], 0, 0, 0);
            accB[c] = __builtin_amdgcn_mfma_f32_16x16x32_bf16(aT, b2l, accB[c], 0, 0, 0);
        }
    }

    if (mode == 0) {
#pragma unroll
        for (int r = 0; r < 4; ++r) {
            int orow = wrow + quad * 4 + r;     // C/D: col = lane&15, row = quad*4 + reg
            float s = sdeg[orow], dv = dinv[orow];
#pragma unroll
            for (int c = 0; c < 8; ++c) {
                int col = c * 16 + m;
                float v = fmaxf(accA[c][r] * s + accB[c][r] + bias[col], 0.f);
                Oy[orow * FEAT + col] = (ushort)bf16rnd(v * dv);
            }
        }
    } else {
        float s0 = sdeg[wrow + quad * 4 + 0];
        float s1 = sdeg[wrow + quad * 4 + 1];
        float s2 = sdeg[wrow + quad * 4 + 2];
        float s3 = sdeg[wrow + quad * 4 + 3];
#pragma unroll
        for (int c = 0; c < 8; ++c) {
            int col = c * 16 + m;
            float bb = bias[col];
            float vm = fmaxf(accA[c][0] * s0 + accB[c][0] + bb, 0.f);
            vm = fmaxf(vm, fmaxf(accA[c][1] * s1 + accB[c][1] + bb, 0.f));
            vm = fmaxf(vm, fmaxf(accA[c][2] * s2 + accB[c][2] + bb, 0.f));
            vm = fmaxf(vm, fmaxf(accA[c][3] * s3 + accB[c][3] + bb, 0.f));
            vm = fmaxf(vm, __shfl_xor(vm, 16));
            vm = fmaxf(vm, __shfl_xor(vm, 32));
            if (lane < 16)
                atomicMax((int*)&hg[g * FEAT + col], __float_as_int(vm));  // vm >= 0, hg 0-init
        }
    }
}

// ---------------- classifier ----------------
__global__ void k_classify(const float* __restrict__ hg, const float* __restrict__ Wc,
                           const float* __restrict__ bc, float* __restrict__ out) {
    int g = blockIdx.x, t = threadIdx.x;
    if (t < NC) {
        float acc = bc[t];
        for (int j = 0; j < FEAT; ++j) acc += hg[g * FEAT + j] * Wc[j * NC + t];
        out[g * NC + t] = acc;
    }
}

extern "C" void kernel_launch(void* const* d_in, const int* in_sizes, int n_in,
                              void* d_out, int out_size, void* d_ws, size_t ws_size,
                              hipStream_t stream) {
    const float* x   = (const float*)d_in[0];
    const float* W1  = (const float*)d_in[1];
    const float* b1  = (const float*)d_in[2];
    const float* W2  = (const float*)d_in[3];
    const float* b2  = (const float*)d_in[4];
    const float* Wc  = (const float*)d_in[5];
    const float* bc  = (const float*)d_in[6];
    const int*   src = (const int*)d_in[7];
    const int*   dst = (const int*)d_in[8];
    float* out = (float*)d_out;

    char* ws = (char*)d_ws;
    size_t off = 0;
    auto alloc = [&](size_t bytes) { char* p = ws + off; off += (bytes + 255) & ~(size_t)255; return p; };
    int*      gcur     = (int*)     alloc(NB * 4);            // contiguous with hg:
    float*    hg       = (float*)   alloc(NB * FEAT * 4);     // one memset covers both
    float*    dinv     = (float*)   alloc(N_NODES * 4);
    float*    sdeg     = (float*)   alloc(N_NODES * 4);
    int*      rowstart = (int*)     alloc((N_NODES + 1) * 4);
    unsigned* gbuf     = (unsigned*)alloc((size_t)NB * BCAP * 4);
    int*      csrc     = (int*)     alloc((size_t)N_EDGES * 4);
    ushort*   W1h      = (ushort*)  alloc(256 * 128 * 2);
    ushort*   W1l      = (ushort*)  alloc(256 * 128 * 2);
    ushort*   W2h      = (ushort*)  alloc(256 * 128 * 2);
    ushort*   W2l      = (ushort*)  alloc(256 * 128 * 2);
    ushort*   Yh       = (ushort*)  alloc((size_t)N_NODES * FEAT * 2);  // dinv*x -> dinv*h
    ushort*   Th       = (ushort*)  alloc((size_t)N_NODES * FEAT * 2);  // T1 -> T2

    hipMemsetAsync(gcur, 0, 256 + NB * FEAT * 4, stream);   // gcur + hg (adjacent)

    // CSR build
    k_binA<<<NBLK_A, 256, 0, stream>>>(src, dst, gbuf, gcur);
    k_prep<<<56, 256, 0, stream>>>(gbuf, gcur, rowstart, dinv, sdeg);
    k_binB<<<224, 256, 0, stream>>>(gbuf, gcur, rowstart, csrc);

    k_packW<<<128, 256, 0, stream>>>(W1, W1h, W1l);
    k_packW<<<128, 256, 0, stream>>>(W2, W2h, W2l);
    k_convert<<<14000, 256, 0, stream>>>(x, dinv, Yh);

    // layer 1 (gemm writes dinv*h into Yh in-place per-row: safe)
    k_gather<<<7000, 256, 0, stream>>>(Yh, dinv, rowstart, csrc, Th);
    k_gemm<<<1792, 256, 0, stream>>>(Yh, Th, W1h, W1l, b1, dinv, sdeg, Yh, nullptr, 0);
    // layer 2 (fused segmax)
    k_gather<<<7000, 256, 0, stream>>>(Yh, dinv, rowstart, csrc, Th);
    k_gemm<<<1792, 256, 0, stream>>>(Yh, Th, W2h, W2l, b2, dinv, sdeg, nullptr, hg, 1);

    k_classify<<<NB, 64, 0, stream>>>(hg, Wc, bc, out);
}

// Round 6
// 354.441 us; speedup vs baseline: 2.1461x; 1.0381x over previous
//
#include <hip/hip_runtime.h>

#define N_NODES 100000
#define N_EDGES 1600000
#define NB      50
#define GSIZE   2000
#define FEAT    128
#define NC      10
#define BCAP    40960      // per-graph bucket capacity (mean 32000, sd ~177)
#define CHUNK   2048       // edges per binA block
#define NBLK_A  782        // ceil(E / CHUNK)
#define STAGE_CAP 12288    // binB stage (span mean 8000, sd ~89)

using short8 = __attribute__((ext_vector_type(8))) short;
using f32x4  = __attribute__((ext_vector_type(4))) float;

__device__ __forceinline__ unsigned bf16rnd(float f) {
    unsigned u = __float_as_uint(f);
    return (u + 0x7fffu + ((u >> 16) & 1u)) >> 16;   // RNE bf16 bits
}
__device__ __forceinline__ float blo(unsigned w) { return __uint_as_float(w << 16); }
__device__ __forceinline__ float bhi(unsigned w) { return __uint_as_float(w & 0xffff0000u); }

// XCD-pinned graph mapping: assumes XCD = blockIdx % 8 round-robin.
// XCD k owns graphs {k, k+8, ..., k+40} plus graph 48 (k=0) / 49 (k=1).
__device__ __forceinline__ int graph_of(int k, int gi) {
    if (gi < 6) return k + 8 * gi;
    return (k < 2) ? (48 + k) : -1;
}

// ---------------- phase A: bin edges into 50 per-graph buckets (LDS-staged) --------
__global__ __launch_bounds__(256) void k_binA(
    const int* __restrict__ src, const int* __restrict__ dst,
    unsigned* __restrict__ gbuf, int* __restrict__ gcur) {
    __shared__ int cnt[NB];
    __shared__ int base[NB];
    __shared__ int gbase[NB];
    __shared__ unsigned stage[CHUNK];
    __shared__ unsigned char bslot[CHUNK];
    __shared__ int total_s;
    int tid = threadIdx.x;
    int e0 = blockIdx.x * CHUNK;
    for (int i = tid; i < NB; i += 256) cnt[i] = 0;
    __syncthreads();

    unsigned pv[8]; int pb[8], pr[8];
#pragma unroll
    for (int q = 0; q < 8; ++q) {
        int e = e0 + q * 256 + tid;
        pb[q] = -1;
        if (e < N_EDGES) {
            int d = dst[e];
            int g = d / 2000;
            pv[q] = ((unsigned)src[e] << 11) | (unsigned)(d - g * 2000);
            pb[q] = g;
            pr[q] = atomicAdd(&cnt[g], 1);
        }
    }
    __syncthreads();
    if (tid == 0) {
        int run = 0;
        for (int b = 0; b < NB; ++b) { base[b] = run; run += cnt[b]; }
        total_s = run;
    }
    __syncthreads();
#pragma unroll
    for (int q = 0; q < 8; ++q) {
        if (pb[q] >= 0) {
            int s = base[pb[q]] + pr[q];
            stage[s] = pv[q];
            bslot[s] = (unsigned char)pb[q];
        }
    }
    if (tid < NB) gbase[tid] = atomicAdd(&gcur[tid], cnt[tid]);
    __syncthreads();
    int total = total_s;
    for (int s = tid; s < total; s += 256) {
        int b = bslot[s];
        gbuf[(size_t)b * BCAP + gbase[b] + (s - base[b])] = stage[s];
    }
}

// ---------------- per-graph: hist + scan -> rowstart, dinv, sdeg -------------------
__global__ __launch_bounds__(256) void k_prep(
    const unsigned* __restrict__ gbuf, const int* __restrict__ gcur,
    int* __restrict__ rowstart, float* __restrict__ dinv, float* __restrict__ sdeg) {
    __shared__ int hist[GSIZE];
    __shared__ int tsum[256];
    __shared__ int goff_s;
    int B = blockIdx.x; int k = B & 7, gi = B >> 3;
    int g = graph_of(k, gi);
    if (g < 0) return;
    int tid = threadIdx.x;
    for (int i = tid; i < GSIZE; i += 256) hist[i] = 0;
    if (tid == 0) { int run = 0; for (int i = 0; i < g; ++i) run += gcur[i]; goff_s = run; }
    __syncthreads();
    int n = gcur[g];
    const unsigned* bp = gbuf + (size_t)g * BCAP;
    for (int i = tid; i < n; i += 256) atomicAdd(&hist[bp[i] & 2047u], 1);
    __syncthreads();
    int base = tid * 8;
    int v[8]; int loc = 0;
#pragma unroll
    for (int q = 0; q < 8; ++q) {
        int idx = base + q;
        v[q] = (idx < GSIZE) ? hist[idx] : 0;
        loc += v[q];
    }
    tsum[tid] = loc; __syncthreads();
    for (int off = 1; off < 256; off <<= 1) {
        int t = (tid >= off) ? tsum[tid - off] : 0;
        __syncthreads(); tsum[tid] += t; __syncthreads();
    }
    int run = goff_s + tsum[tid] - loc;
#pragma unroll
    for (int q = 0; q < 8; ++q) {
        int idx = base + q;
        if (idx < GSIZE) {
            int node = g * GSIZE + idx;
            rowstart[node] = run;
            float d = fmaxf((float)v[q], 1.f);
            dinv[node] = rsqrtf(d);
            sdeg[node] = sqrtf(d);
            run += v[q];
        }
    }
    if (tid == 0) rowstart[g * GSIZE + GSIZE] = goff_s + n;  // == next graph's start
}

// ---------------- phase B: build csrc in LDS, write coalesced ----------------------
__global__ __launch_bounds__(256) void k_binB(
    const unsigned* __restrict__ gbuf, const int* __restrict__ gcur,
    const int* __restrict__ rowstart, int* __restrict__ csrc) {
    __shared__ int lcur[500];
    __shared__ int stage[STAGE_CAP];
    int B = blockIdx.x; int k = B & 7, j = B >> 3;
    int gi = j >> 2, q = j & 3;
    int g = graph_of(k, gi);
    if (g < 0) return;
    int tid = threadIdx.x;
    int n0 = g * GSIZE + q * 500;
    int n0l = q * 500;
    int span0 = rowstart[n0];
    int span  = rowstart[n0 + 500] - span0;
    for (int i = tid; i < 500; i += 256) lcur[i] = rowstart[n0 + i] - span0;
    __syncthreads();
    int n = gcur[g];
    const unsigned* bp = gbuf + (size_t)g * BCAP;
    for (int i = tid; i < n; i += 256) {
        unsigned v = bp[i];
        unsigned d = (v & 2047u) - (unsigned)n0l;
        if (d < 500u) {
            int p = atomicAdd(&lcur[d], 1);
            stage[p] = (int)(v >> 11);
        }
    }
    __syncthreads();
    for (int s = tid; s < span; s += 256)
        csrc[span0 + s] = stage[s];
}

// ---------------- convert: Yh = bf16(dinv * x) (XCD-pinned per graph) --------------
__global__ __launch_bounds__(256) void k_convert(const float* __restrict__ x,
                          const float* __restrict__ dinv, ushort* __restrict__ Yh) {
    int B = blockIdx.x; int k = B & 7, j = B >> 3;
    int gi = j / 250, local = j % 250;
    int g = graph_of(k, gi);
    if (g < 0) return;
    int tid = threadIdx.x;
    int r = tid >> 5, c = tid & 31;
    int node = g * GSIZE + local * 8 + r;
    float dv = dinv[node];
    float4 v = ((const float4*)x)[node * 32 + c];
    uint2 yo;
    yo.x = bf16rnd(v.x * dv) | (bf16rnd(v.y * dv) << 16);
    yo.y = bf16rnd(v.z * dv) | (bf16rnd(v.w * dv) << 16);
    ((uint2*)Yh)[node * 32 + c] = yo;
}

// ---------------- pack W (256x128) into MFMA B-fragment layout, hi/lo --------------
__global__ void k_packW(const float* __restrict__ W,
                        ushort* __restrict__ Wh, ushort* __restrict__ Wl) {
    int idx = blockIdx.x * 256 + threadIdx.x;   // 0..32767
    int j = idx & 7, l = (idx >> 3) & 63, kb = (idx >> 9) & 7, c = idx >> 12;
    int k = kb * 32 + (l >> 4) * 8 + j;
    int col = c * 16 + (l & 15);
    float w = W[k * 128 + col];
    unsigned h = bf16rnd(w);
    float rem = w - __uint_as_float(h << 16);
    Wh[idx] = (ushort)h;
    Wl[idx] = (ushort)bf16rnd(rem);
}

// ---------------- gather: T[n] = bf16( -dinv[n] * sum_e Yh[csrc[e]] ) --------------
// XCD-pinned: 16 nodes/block, 16 lanes/node, 16B loads. Row = 16 uint4 (256 B).
__global__ __launch_bounds__(256) void k_gather(
    const ushort* __restrict__ Yh, const float* __restrict__ dinv,
    const int* __restrict__ rowstart, const int* __restrict__ csrc,
    ushort* __restrict__ Th) {
    int B = blockIdx.x; int k = B & 7, j = B >> 3;
    int gi = j / 125, local = j % 125;
    int g = graph_of(k, gi);
    if (g < 0) return;
    int tid = threadIdx.x;
    int c = tid & 15;          // 16B column group 0..15
    int i = tid >> 4;          // node 0..15
    int n = g * GSIZE + local * 16 + i;
    int rs = rowstart[n], re = rowstart[n + 1];
    const uint4* Y4 = (const uint4*)Yh;
    float a0=0.f,a1=0.f,a2=0.f,a3=0.f,a4=0.f,a5=0.f,a6=0.f,a7=0.f;
    float d0=0.f,d1=0.f,d2=0.f,d3=0.f,d4=0.f,d5=0.f,d6=0.f,d7=0.f;
    int e = rs;
    for (; e + 1 < re; e += 2) {
        int s0 = csrc[e], s1 = csrc[e + 1];
        uint4 u = Y4[s0 * 16 + c];
        uint4 w = Y4[s1 * 16 + c];
        a0 += blo(u.x); a1 += bhi(u.x); a2 += blo(u.y); a3 += bhi(u.y);
        a4 += blo(u.z); a5 += bhi(u.z); a6 += blo(u.w); a7 += bhi(u.w);
        d0 += blo(w.x); d1 += bhi(w.x); d2 += blo(w.y); d3 += bhi(w.y);
        d4 += blo(w.z); d5 += bhi(w.z); d6 += blo(w.w); d7 += bhi(w.w);
    }
    if (e < re) {
        uint4 u = Y4[csrc[e] * 16 + c];
        a0 += blo(u.x); a1 += bhi(u.x); a2 += blo(u.y); a3 += bhi(u.y);
        a4 += blo(u.z); a5 += bhi(u.z); a6 += blo(u.w); a7 += bhi(u.w);
    }
    a0+=d0; a1+=d1; a2+=d2; a3+=d3; a4+=d4; a5+=d5; a6+=d6; a7+=d7;
    float dn = -dinv[n];
    uint4 o;
    o.x = bf16rnd(a0 * dn) | (bf16rnd(a1 * dn) << 16);
    o.y = bf16rnd(a2 * dn) | (bf16rnd(a3 * dn) << 16);
    o.z = bf16rnd(a4 * dn) | (bf16rnd(a5 * dn) << 16);
    o.w = bf16rnd(a6 * dn) | (bf16rnd(a7 * dn) << 16);
    ((uint4*)Th)[n * 16 + c] = o;
}

// ---------------- weight-stationary MFMA GEMM ---------------------------------------
// out = relu(sdeg_row*(Y@Wa) + T@Wb + b). Wave w owns c-tiles {w, w+4}; its 32
// B-fragments (2c x 8kb x hi/lo) live in registers; loops 5 row-tiles (80 rows/block).
// mode 0: Oy = bf16(out * dinv[row]).  mode 1: fused segment-max into hg.
__global__ __launch_bounds__(256, 2) void k_gemm(
    const ushort* __restrict__ Yh, const ushort* __restrict__ Th,
    const ushort* __restrict__ Wh, const ushort* __restrict__ Wl,
    const float* __restrict__ bias, const float* __restrict__ dinv,
    const float* __restrict__ sdeg,
    ushort* __restrict__ Oy, float* __restrict__ hg, int mode) {
    int B = blockIdx.x; int k = B & 7, j = B >> 3;
    int gi = j / 25, local = j % 25;
    int g = graph_of(k, gi);
    if (g < 0) return;
    int tid = threadIdx.x;
    int lane = tid & 63, wave = tid >> 6;
    int m = lane & 15, quad = lane >> 4;
    int rowbase = g * GSIZE + local * 80;
    int col0 = wave * 16 + m, col1 = (wave + 4) * 16 + m;

    // load B fragments once (register-resident weights)
    short8 bh[2][8], bl[2][8];
#pragma unroll
    for (int ci = 0; ci < 2; ++ci) {
        int c = wave + ci * 4;
#pragma unroll
        for (int kb = 0; kb < 8; ++kb) {
            int bo = ((c * 8 + kb) * 64 + lane) * 8;
            bh[ci][kb] = *reinterpret_cast<const short8*>(Wh + bo);
            bl[ci][kb] = *reinterpret_cast<const short8*>(Wl + bo);
        }
    }
    float bb0 = bias[col0], bb1 = bias[col1];
    float run0 = 0.f, run1 = 0.f;

#pragma unroll 1
    for (int rt = 0; rt < 5; ++rt) {
        int wrow = rowbase + rt * 16;
        int row = wrow + m;
        f32x4 aA0 = {0.f,0.f,0.f,0.f}, aB0 = {0.f,0.f,0.f,0.f};
        f32x4 aA1 = {0.f,0.f,0.f,0.f}, aB1 = {0.f,0.f,0.f,0.f};
#pragma unroll
        for (int kb = 0; kb < 4; ++kb) {
            int ko = kb * 32 + quad * 8;
            short8 aY = *reinterpret_cast<const short8*>(Yh + row * FEAT + ko);
            short8 aT = *reinterpret_cast<const short8*>(Th + row * FEAT + ko);
            aA0 = __builtin_amdgcn_mfma_f32_16x16x32_bf16(aY, bh[0][kb],     aA0, 0, 0, 0);
            aA0 = __builtin_amdgcn_mfma_f32_16x16x32_bf16(aY, bl[0][kb],     aA0, 0, 0, 0);
            aB0 = __builtin_amdgcn_mfma_f32_16x16x32_bf16(aT, bh[0][kb + 4], aB0, 0, 0, 0);
            aB0 = __builtin_amdgcn_mfma_f32_16x16x32_bf16(aT, bl[0][kb + 4], aB0, 0, 0, 0);
            aA1 = __builtin_amdgcn_mfma_f32_16x16x32_bf16(aY, bh[1][kb],     aA1, 0, 0, 0);
            aA1 = __builtin_amdgcn_mfma_f32_16x16x32_bf16(aY, bl[1][kb],     aA1, 0, 0, 0);
            aB1 = __builtin_amdgcn_mfma_f32_16x16x32_bf16(aT, bh[1][kb + 4], aB1, 0, 0, 0);
            aB1 = __builtin_amdgcn_mfma_f32_16x16x32_bf16(aT, bl[1][kb + 4], aB1, 0, 0, 0);
        }
        if (mode == 0) {
#pragma unroll
            for (int r = 0; r < 4; ++r) {
                int orow = wrow + quad * 4 + r;   // C/D: col = lane&15, row = quad*4 + reg
                float s = sdeg[orow], dv = dinv[orow];
                float v0 = fmaxf(aA0[r] * s + aB0[r] + bb0, 0.f);
                float v1 = fmaxf(aA1[r] * s + aB1[r] + bb1, 0.f);
                Oy[orow * FEAT + col0] = (ushort)bf16rnd(v0 * dv);
                Oy[orow * FEAT + col1] = (ushort)bf16rnd(v1 * dv);
            }
        } else {
#pragma unroll
            for (int r = 0; r < 4; ++r) {
                float s = sdeg[wrow + quad * 4 + r];
                run0 = fmaxf(run0, fmaxf(aA0[r] * s + aB0[r] + bb0, 0.f));
                run1 = fmaxf(run1, fmaxf(aA1[r] * s + aB1[r] + bb1, 0.f));
            }
        }
    }
    if (mode == 1) {
        run0 = fmaxf(run0, __shfl_xor(run0, 16));
        run0 = fmaxf(run0, __shfl_xor(run0, 32));
        run1 = fmaxf(run1, __shfl_xor(run1, 16));
        run1 = fmaxf(run1, __shfl_xor(run1, 32));
        if (lane < 16) {
            atomicMax((int*)&hg[g * FEAT + col0], __float_as_int(run0));  // vals >= 0, hg 0-init
            atomicMax((int*)&hg[g * FEAT + col1], __float_as_int(run1));
        }
    }
}

// ---------------- classifier ----------------
__global__ void k_classify(const float* __restrict__ hg, const float* __restrict__ Wc,
                           const float* __restrict__ bc, float* __restrict__ out) {
    int g = blockIdx.x, t = threadIdx.x;
    if (t < NC) {
        float acc = bc[t];
        for (int j = 0; j < FEAT; ++j) acc += hg[g * FEAT + j] * Wc[j * NC + t];
        out[g * NC + t] = acc;
    }
}

extern "C" void kernel_launch(void* const* d_in, const int* in_sizes, int n_in,
                              void* d_out, int out_size, void* d_ws, size_t ws_size,
                              hipStream_t stream) {
    const float* x   = (const float*)d_in[0];
    const float* W1  = (const float*)d_in[1];
    const float* b1  = (const float*)d_in[2];
    const float* W2  = (const float*)d_in[3];
    const float* b2  = (const float*)d_in[4];
    const float* Wc  = (const float*)d_in[5];
    const float* bc  = (const float*)d_in[6];
    const int*   src = (const int*)d_in[7];
    const int*   dst = (const int*)d_in[8];
    float* out = (float*)d_out;

    char* ws = (char*)d_ws;
    size_t off = 0;
    auto alloc = [&](size_t bytes) { char* p = ws + off; off += (bytes + 255) & ~(size_t)255; return p; };
    int*      gcur     = (int*)     alloc(NB * 4);            // contiguous with hg:
    float*    hg       = (float*)   alloc(NB * FEAT * 4);     // one memset covers both
    float*    dinv     = (float*)   alloc(N_NODES * 4);
    float*    sdeg     = (float*)   alloc(N_NODES * 4);
    int*      rowstart = (int*)     alloc((N_NODES + 1) * 4);
    unsigned* gbuf     = (unsigned*)alloc((size_t)NB * BCAP * 4);
    int*      csrc     = (int*)     alloc((size_t)N_EDGES * 4);
    ushort*   W1h      = (ushort*)  alloc(256 * 128 * 2);
    ushort*   W1l      = (ushort*)  alloc(256 * 128 * 2);
    ushort*   W2h      = (ushort*)  alloc(256 * 128 * 2);
    ushort*   W2l      = (ushort*)  alloc(256 * 128 * 2);
    ushort*   Yh       = (ushort*)  alloc((size_t)N_NODES * FEAT * 2);  // dinv*x -> dinv*h
    ushort*   Th       = (ushort*)  alloc((size_t)N_NODES * FEAT * 2);  // T1 -> T2

    hipMemsetAsync(gcur, 0, 256 + NB * FEAT * 4, stream);   // gcur + hg (adjacent)

    // CSR build
    k_binA<<<NBLK_A, 256, 0, stream>>>(src, dst, gbuf, gcur);
    k_prep<<<56, 256, 0, stream>>>(gbuf, gcur, rowstart, dinv, sdeg);
    k_binB<<<224, 256, 0, stream>>>(gbuf, gcur, rowstart, csrc);

    k_packW<<<128, 256, 0, stream>>>(W1, W1h, W1l);
    k_packW<<<128, 256, 0, stream>>>(W2, W2h, W2l);
    k_convert<<<14000, 256, 0, stream>>>(x, dinv, Yh);

    // layer 1 (gemm writes dinv*h into Yh in-place per-row: safe)
    k_gather<<<7000, 256, 0, stream>>>(Yh, dinv, rowstart, csrc, Th);
    k_gemm<<<1400, 256, 0, stream>>>(Yh, Th, W1h, W1l, b1, dinv, sdeg, Yh, nullptr, 0);
    // layer 2 (fused segmax)
    k_gather<<<7000, 256, 0, stream>>>(Yh, dinv, rowstart, csrc, Th);
    k_gemm<<<1400, 256, 0, stream>>>(Yh, Th, W2h, W2l, b2, dinv, sdeg, nullptr, hg, 1);

    k_classify<<<NB, 64, 0, stream>>>(hg, Wc, bc, out);
}